// Round 9
// baseline (596.530 us; speedup 1.0000x reference)
//
#include <hip/hip_runtime.h>
#include <stdint.h>

#define HH 64      // hidden
#define II 32      // input features
#define TSTEPS 512
#define BATCH 1024
#define CH 64      // timesteps per x-chunk (64*32 floats = 8KB per batch)
#define NCH (TSTEPS / CH)

typedef float f32x2 __attribute__((ext_vector_type(2)));
typedef float f32x4 __attribute__((ext_vector_type(4)));

// tanh(x) = 1 - 2/(exp(2x)+1); hw exp2 + hw rcp; saturates correctly at +/-inf
__device__ __forceinline__ float fast_tanh(float x) {
    float e = __builtin_amdgcn_exp2f(x * 2.885390081777927f); // 2*log2(e)
    return fmaf(-2.0f, __builtin_amdgcn_rcpf(e + 1.0f), 1.0f);
}

// load a row of N floats into f32x2 pairs via float4 loads
#define LOADW2(dst, src, N)                                                   \
    {                                                                         \
        const f32x4* p_ = (const f32x4*)(src);                                \
        _Pragma("unroll") for (int k_ = 0; k_ < (N) / 4; ++k_) {              \
            f32x4 v_ = p_[k_];                                                \
            dst[2 * k_] = v_.lo;                                              \
            dst[2 * k_ + 1] = v_.hi;                                          \
        }                                                                     \
    }

// LDS-ordering barrier (lgkmcnt only; staging vmcnt stays in flight)
#define LDS_BARRIER()                                                         \
    {                                                                         \
        asm volatile("s_waitcnt lgkmcnt(0)" ::: "memory");                    \
        asm volatile("s_barrier" ::: "memory");                               \
    }

// Fused single kernel: 1 block = 2 batch elements, 2 waves, split-K.
// lane l of wave w: output o = w*32+(l&31), K-half kh = l>>5.
// Two independent batch recurrences interleaved per step for ILP.
__global__ void __launch_bounds__(128, 2) rnn_fused2(
    const float* __restrict__ x,     // [B,T,II]
    const float* __restrict__ Wih1,  // [H,II]
    const float* __restrict__ Whh1,  // [H,H]
    const float* __restrict__ bih1,
    const float* __restrict__ bhh1,
    const float* __restrict__ Wih2,  // [H,H]
    const float* __restrict__ Whh2,  // [H,H]
    const float* __restrict__ bih2,
    const float* __restrict__ bhh2,
    const float* __restrict__ Wfc1,  // [H,H]
    const float* __restrict__ bfc1,
    const float* __restrict__ Wfc2,  // [32,H]
    const float* __restrict__ bfc2,
    float* __restrict__ out)         // [B,32]
{
    const int tid = threadIdx.x;
    const int w = tid >> 6;          // wave 0/1
    const int l = tid & 63;
    const int o = w * 32 + (l & 31); // owned output row
    const int kh = l >> 5;           // K-half
    const int b0 = blockIdx.x * 2;   // this block's two batch elements

    __shared__ __align__(16) float xs[2][2][CH * II]; // [buf][batch] 32 KB
    __shared__ __align__(16) float hb1[2][HH];        // h1(t) exchange per batch
    __shared__ __align__(16) float hb2[2][2][HH];     // [parity][batch]
    __shared__ __align__(16) float zb[2][HH];         // FC z exchange

    // ---- resident weights: 112 VGPRs ----
    f32x2 wih1h[8], whh1v[16], wih2v[16], whh2v[16];
    LOADW2(wih1h, Wih1 + o * II + kh * 16, 16);
    LOADW2(whh1v, Whh1 + o * HH + kh * 32, 32);
    LOADW2(wih2v, Wih2 + o * HH + kh * 32, 32);
    LOADW2(whh2v, Whh2 + o * HH + kh * 32, 32);
    const float b1h = kh ? 0.f : (bih1[o] + bhh1[o]);  // bias once per reduce
    const float b2  = bih2[o] + bhh2[o];

    hb2[0][tid >> 6][tid & 63] = 0.f;  // h2(-1) = 0, both batches

    const float* xbs = x + (size_t)(b0 + w) * TSTEPS * II;  // wave w stages batch w

// stage one 8KB chunk (wave w -> batch w's buffer)
#define STAGE(cidx, bufi)                                                     \
    {                                                                         \
        const float* ss_ = xbs + (size_t)(cidx) * CH * II;                    \
        _Pragma("unroll") for (int k_ = 0; k_ < 8; ++k_) {                    \
            __builtin_amdgcn_global_load_lds(                                 \
                (const __attribute__((address_space(1))) void*)(ss_ + k_ * 256 + l * 4), \
                (__attribute__((address_space(3))) void*)(&xs[bufi][w][k_ * 256]), \
                16, 0, 0);                                                    \
        }                                                                     \
    }

    STAGE(0, 0)
    asm volatile("s_waitcnt vmcnt(0) lgkmcnt(0)" ::: "memory");
    asm volatile("s_barrier" ::: "memory");  // staging + hb2 zero visible

    f32x2 h1v0[16], h1v1[16];  // h1(t-1) halves per batch, register-resident
#pragma unroll
    for (int k = 0; k < 16; ++k) { h1v0[k] = f32x2{0.f, 0.f}; h1v1[k] = f32x2{0.f, 0.f}; }

// One step at compile-time parity P, timestep TT within current chunk.
// Both batches interleaved: independent chains hide LDS/shfl/tanh latency.
#define STEP(P, TT)                                                           \
    {                                                                         \
        const float* xr0 = &xs[buf][0][(TT) * II + kh * 16];                  \
        const float* xr1 = &xs[buf][1][(TT) * II + kh * 16];                  \
        f32x2 r0a = {b1h, 0.f}, r0b = {0.f, 0.f};  /* b0: x + Whh1@h1 */      \
        f32x2 r1a = {b1h, 0.f}, r1b = {0.f, 0.f};  /* b1 */                   \
        f32x2 q0a = {0.f, 0.f}, q0b = {0.f, 0.f};  /* b0: Whh2@h2prev */      \
        f32x2 q1a = {0.f, 0.f}, q1b = {0.f, 0.f};  /* b1 */                   \
        _Pragma("unroll") for (int k = 0; k < 4; ++k) {                       \
            f32x4 xq0 = *(const f32x4*)(xr0 + 4 * k);  /* uniform per kh */   \
            f32x4 xq1 = *(const f32x4*)(xr1 + 4 * k);                         \
            r0a = __builtin_elementwise_fma(xq0.lo, wih1h[2 * k], r0a);       \
            r0b = __builtin_elementwise_fma(xq0.hi, wih1h[2 * k + 1], r0b);   \
            r1a = __builtin_elementwise_fma(xq1.lo, wih1h[2 * k], r1a);       \
            r1b = __builtin_elementwise_fma(xq1.hi, wih1h[2 * k + 1], r1b);   \
        }                                                                     \
        _Pragma("unroll") for (int k = 0; k < 8; ++k) {                       \
            f32x4 h20 = *(const f32x4*)(&hb2[P][0][kh * 32 + 4 * k]);         \
            f32x4 h21 = *(const f32x4*)(&hb2[P][1][kh * 32 + 4 * k]);         \
            q0a = __builtin_elementwise_fma(h20.lo, whh2v[2 * k], q0a);       \
            q0b = __builtin_elementwise_fma(h20.hi, whh2v[2 * k + 1], q0b);   \
            q1a = __builtin_elementwise_fma(h21.lo, whh2v[2 * k], q1a);       \
            q1b = __builtin_elementwise_fma(h21.hi, whh2v[2 * k + 1], q1b);   \
            r0a = __builtin_elementwise_fma(h1v0[2 * k], whh1v[2 * k], r0a);  \
            r0b = __builtin_elementwise_fma(h1v0[2 * k + 1], whh1v[2 * k + 1], r0b); \
            r1a = __builtin_elementwise_fma(h1v1[2 * k], whh1v[2 * k], r1a);  \
            r1b = __builtin_elementwise_fma(h1v1[2 * k + 1], whh1v[2 * k + 1], r1b); \
        }                                                                     \
        const float y2c0 = (q0a.x + q0a.y) + (q0b.x + q0b.y);                 \
        const float y2c1 = (q1a.x + q1a.y) + (q1b.x + q1b.y);                 \
        float y10 = (r0a.x + r0a.y) + (r0b.x + r0b.y);                        \
        float y11 = (r1a.x + r1a.y) + (r1b.x + r1b.y);                        \
        const float h10 = fast_tanh(y10 + __shfl_xor(y10, 32));               \
        const float h11 = fast_tanh(y11 + __shfl_xor(y11, 32));               \
        if (l < 32) { hb1[0][o] = h10; hb1[1][o] = h11; }                     \
        LDS_BARRIER() /* h1 visible */                                        \
        f32x2 s0a = {0.f, 0.f}, s0b = {0.f, 0.f};                             \
        f32x2 s1a = {0.f, 0.f}, s1b = {0.f, 0.f};                             \
        _Pragma("unroll") for (int k = 0; k < 8; ++k) {                       \
            f32x4 hq0 = *(const f32x4*)(&hb1[0][kh * 32 + 4 * k]);            \
            f32x4 hq1 = *(const f32x4*)(&hb1[1][kh * 32 + 4 * k]);            \
            h1v0[2 * k] = hq0.lo; h1v0[2 * k + 1] = hq0.hi;                   \
            h1v1[2 * k] = hq1.lo; h1v1[2 * k + 1] = hq1.hi;                   \
            s0a = __builtin_elementwise_fma(hq0.lo, wih2v[2 * k], s0a);       \
            s0b = __builtin_elementwise_fma(hq0.hi, wih2v[2 * k + 1], s0b);   \
            s1a = __builtin_elementwise_fma(hq1.lo, wih2v[2 * k], s1a);       \
            s1b = __builtin_elementwise_fma(hq1.hi, wih2v[2 * k + 1], s1b);   \
        }                                                                     \
        float y20 = (s0a.x + s0a.y) + (s0b.x + s0b.y) + y2c0;                 \
        float y21 = (s1a.x + s1a.y) + (s1b.x + s1b.y) + y2c1;                 \
        const float h20v = fast_tanh(b2 + y20 + __shfl_xor(y20, 32));         \
        const float h21v = fast_tanh(b2 + y21 + __shfl_xor(y21, 32));         \
        if (l < 32) { hb2[(P) ^ 1][0][o] = h20v; hb2[(P) ^ 1][1][o] = h21v; } \
        LDS_BARRIER() /* h2 visible; hb1 reusable */                          \
    }

#pragma unroll 1
    for (int c = 0; c < NCH; ++c) {
        const int buf = c & 1;
        if (c + 1 < NCH) STAGE(c + 1, buf ^ 1)
#pragma unroll 1
        for (int tt = 0; tt < CH; tt += 2) {
            STEP(0, tt)
            STEP(1, tt + 1)
        }
        // both waves' staging must have landed before buffer swap
        asm volatile("s_waitcnt vmcnt(0)" ::: "memory");
        asm volatile("s_barrier" ::: "memory");
    }

    // ---- FC head; final h2 in hb2[0][batch] (last STEP has P=1 -> writes [0]) ----
    {
        f32x2 wf[16];
        LOADW2(wf, Wfc1 + o * HH + kh * 32, 32);
        f32x2 u0a = {0.f, 0.f}, u0b = {0.f, 0.f}, u1a = {0.f, 0.f}, u1b = {0.f, 0.f};
#pragma unroll
        for (int k = 0; k < 8; ++k) {
            f32x4 h0 = *(const f32x4*)(&hb2[0][0][kh * 32 + 4 * k]);
            f32x4 h1 = *(const f32x4*)(&hb2[0][1][kh * 32 + 4 * k]);
            u0a = __builtin_elementwise_fma(h0.lo, wf[2 * k], u0a);
            u0b = __builtin_elementwise_fma(h0.hi, wf[2 * k + 1], u0b);
            u1a = __builtin_elementwise_fma(h1.lo, wf[2 * k], u1a);
            u1b = __builtin_elementwise_fma(h1.hi, wf[2 * k + 1], u1b);
        }
        float z0 = (u0a.x + u0a.y) + (u0b.x + u0b.y);
        float z1 = (u1a.x + u1a.y) + (u1b.x + u1b.y);
        const float zz0 = fmaxf(bfc1[o] + z0 + __shfl_xor(z0, 32), 0.f);
        const float zz1 = fmaxf(bfc1[o] + z1 + __shfl_xor(z1, 32), 0.f);
        if (l < 32) { zb[0][o] = zz0; zb[1][o] = zz1; }
        __syncthreads();
    }
    {
        const int ow = w * 16 + (l & 15);  // 32 outputs across 2 waves
        const int kq = l >> 4;             // K-quarter (16 floats)
        f32x2 wg[8];
        LOADW2(wg, Wfc2 + ow * HH + kq * 16, 16);
        f32x2 u0a = {0.f, 0.f}, u0b = {0.f, 0.f}, u1a = {0.f, 0.f}, u1b = {0.f, 0.f};
#pragma unroll
        for (int k = 0; k < 4; ++k) {
            f32x4 z0 = *(const f32x4*)(&zb[0][kq * 16 + 4 * k]);
            f32x4 z1 = *(const f32x4*)(&zb[1][kq * 16 + 4 * k]);
            u0a = __builtin_elementwise_fma(z0.lo, wg[2 * k], u0a);
            u0b = __builtin_elementwise_fma(z0.hi, wg[2 * k + 1], u0b);
            u1a = __builtin_elementwise_fma(z1.lo, wg[2 * k], u1a);
            u1b = __builtin_elementwise_fma(z1.hi, wg[2 * k + 1], u1b);
        }
        float v0 = (u0a.x + u0a.y) + (u0b.x + u0b.y);
        float v1 = (u1a.x + u1a.y) + (u1b.x + u1b.y);
        v0 += __shfl_xor(v0, 16); v0 += __shfl_xor(v0, 32);
        v1 += __shfl_xor(v1, 16); v1 += __shfl_xor(v1, 32);
        if (l < 16) {
            out[(b0 + 0) * 32 + ow] = bfc2[ow] + v0;
            out[(b0 + 1) * 32 + ow] = bfc2[ow] + v1;
        }
    }
}

extern "C" void kernel_launch(void* const* d_in, const int* in_sizes, int n_in,
                              void* d_out, int out_size, void* d_ws, size_t ws_size,
                              hipStream_t stream) {
    const float* x    = (const float*)d_in[0];
    const float* Wih1 = (const float*)d_in[1];
    const float* Whh1 = (const float*)d_in[2];
    const float* bih1 = (const float*)d_in[3];
    const float* bhh1 = (const float*)d_in[4];
    const float* Wih2 = (const float*)d_in[5];
    const float* Whh2 = (const float*)d_in[6];
    const float* bih2 = (const float*)d_in[7];
    const float* bhh2 = (const float*)d_in[8];
    const float* Wfc1 = (const float*)d_in[9];
    const float* bfc1 = (const float*)d_in[10];
    const float* Wfc2 = (const float*)d_in[11];
    const float* bfc2 = (const float*)d_in[12];
    float* out = (float*)d_out;

    hipLaunchKernelGGL(rnn_fused2, dim3(BATCH / 2), dim3(128), 0, stream,
                       x, Wih1, Whh1, bih1, bhh1, Wih2, Whh2, bih2, bhh2,
                       Wfc1, bfc1, Wfc2, bfc2, out);
}